// Round 9
// baseline (113.545 us; speedup 1.0000x reference)
//
#include <hip/hip_runtime.h>
#include <hip/hip_bf16.h>
#include <math.h>

#define MM 8192
#define CC 4096
#define DD 768
#define EPSF 1e-8f

#define BM 256
#define BN 256
#define BK 64
#define TPB 512
#define NKT (DD / BK)          // 12 K-tiles
#define NROWT (MM / BM)        // 32
#define NCOLT (CC / BN)        // 16

// ---- ws layout ----
#define XB_OFF 0
#define YB_OFF (MM * DD * 2)
#define FW_OFF (YB_OFF + CC * DD * 2)
#define S_T 0
#define T_T (MM)
#define S_L (2 * MM)
#define T_L (2 * MM + CC)
#define CA_T (2 * MM + 2 * CC)         // t_t / s_t per text row
#define POS  (CA_T + MM)
#define PART (POS + MM)                // MM * NCOLT * 2 floats (top-2 largest u)

typedef __attribute__((ext_vector_type(8))) short short8;
typedef __attribute__((ext_vector_type(4))) unsigned short u16x4;
typedef __attribute__((ext_vector_type(4))) float f32x4;

__device__ inline unsigned short f2bf(float f) {
    unsigned int u = __float_as_uint(f);
    u += 0x7FFF + ((u >> 16) & 1);   // RNE
    return (unsigned short)(u >> 16);
}

__device__ inline void gll16(const void* g, void* l) {
    __builtin_amdgcn_global_load_lds(
        (const __attribute__((address_space(1))) void*)(uintptr_t)g,
        (__attribute__((address_space(3))) void*)(unsigned)(uintptr_t)l,
        16, 0, 0);
}

#define BAR() do { __builtin_amdgcn_sched_barrier(0); __builtin_amdgcn_s_barrier(); __builtin_amdgcn_sched_barrier(0); } while (0)
#define VM8 asm volatile("s_waitcnt vmcnt(8)" ::: "memory")
#define VM4 asm volatile("s_waitcnt vmcnt(4)" ::: "memory")
#define VM0 asm volatile("s_waitcnt vmcnt(0)" ::: "memory")
#define NOPS ((void)0)

#define DSR(dst, base, off) \
    asm volatile("ds_read_b128 %0, %1 offset:%c2" : "=v"(dst) : "v"(base), "n"(off))

#define MFMA_B(a, b, c) __builtin_amdgcn_mfma_f32_16x16x32_bf16((a), (b), (c), 0, 0, 0)

// ---------------- prep+convert: per-row s,t,ca + bf16 copies (XCD-local X rows) ----------------
__global__ void prep_conv_kernel(const float* __restrict__ X, const float* __restrict__ Y,
                                 const float* curv_log, const float* ta_log, const float* la_log,
                                 char* __restrict__ wsb) {
    unsigned short* Xb = (unsigned short*)(wsb + XB_OFF);
    unsigned short* Yb = (unsigned short*)(wsb + YB_OFF);
    float* fws = (float*)(wsb + FW_OFF);
    int wid = threadIdx.x >> 6, lane = threadIdx.x & 63;
    int b = blockIdx.x;
    // X blocks [0,2048): XCD b%8 writes rows [ (b%8)*1024 + (b/8)*4 , +4 ) -> main kernel's
    // XCD x reads exactly rows [1024x,1024x+1024) => A-panel staged from local dirty L2.
    int row;
    if (b < MM / 4) row = (b & 7) * 1024 + (b >> 3) * 4 + wid;
    else            row = b * 4 + wid;     // Y rows: global reuse, leave round-robin
    float curv = __expf(curv_log[0]);
    const float* src; unsigned short* dst; float alpha; int idx; int is_text;
    if (row < MM) {
        src = X + (size_t)row * DD; dst = Xb + (size_t)row * DD;
        alpha = __expf(ta_log[0]); idx = row; is_text = 1;
    } else {
        int r = row - MM;
        src = Y + (size_t)r * DD; dst = Yb + (size_t)r * DD;
        alpha = __expf(la_log[0]); idx = r; is_text = 0;
    }
    float n2 = 0.f;
    #pragma unroll
    for (int j = 0; j < 3; ++j) {
        float4 v = *(const float4*)(src + lane * 4 + 256 * j);
        n2 += v.x * v.x + v.y * v.y + v.z * v.z + v.w * v.w;
        u16x4 o; o[0] = f2bf(v.x); o[1] = f2bf(v.y); o[2] = f2bf(v.z); o[3] = f2bf(v.w);
        *(u16x4*)(dst + lane * 4 + 256 * j) = o;
    }
    #pragma unroll
    for (int m = 32; m; m >>= 1) n2 += __shfl_xor(n2, m);
    if (lane == 0) {
        float r = sqrtf(curv) * alpha * sqrtf(n2);
        float s = alpha * sinhf(r) / fmaxf(r, EPSF);
        float tt = sqrtf(1.0f / curv + s * s * n2);
        if (is_text) {
            fws[S_T + idx] = s; fws[T_T + idx] = tt; fws[CA_T + idx] = tt / s;
        } else {
            fws[S_L + idx] = s; fws[T_L + idx] = tt;
        }
    }
}

// ---------------- pos: exact fp32 positive distance ----------------
__global__ void pos_kernel(const float* __restrict__ X, const float* __restrict__ Y,
                           const int* __restrict__ tgt, const float* curv_log,
                           char* __restrict__ wsb) {
    float* fws = (float*)(wsb + FW_OFF);
    int wid = threadIdx.x >> 6, lane = threadIdx.x & 63;
    int row = blockIdx.x * 4 + wid;
    if (row >= MM) return;
    float curv = __expf(curv_log[0]);
    int t = tgt[row];
    const float* xr = X + (size_t)row * DD;
    const float* yr = Y + (size_t)t * DD;
    float dot = 0.f;
    #pragma unroll
    for (int k = 0; k < DD / 64; ++k) dot += xr[lane + 64 * k] * yr[lane + 64 * k];
    #pragma unroll
    for (int m = 32; m; m >>= 1) dot += __shfl_xor(dot, m);
    if (lane == 0) {
        float inner = fws[S_T + row] * fws[S_L + t] * dot - fws[T_T + row] * fws[T_L + t];
        float cd = fmaxf(-curv * inner, 1.0f + EPSF);
        float d = __logf(cd + sqrtf(cd * cd - 1.0f)) * rsqrtf(curv);
        fws[POS + row] = d;
    }
}

// ---------------- main: 256x256, 24 merged phases (32 MFMA each), 2 barriers/phase ----------------
__global__ __launch_bounds__(TPB) void main_kernel(
    const int* __restrict__ tgt, char* __restrict__ wsb)
{
    // region rg = (kt&1)*2 + kh; [row 0..255][k-slot 0..3], 64B rows, XOR-swizzled, 16KB each.
    __shared__ unsigned short Ald[4 * 8192];   // 64KB
    __shared__ unsigned short Bld[4 * 8192];   // 64KB
    __shared__ float red[256][4][2];           // 8KB

    const unsigned short* Xb = (const unsigned short*)(wsb + XB_OFF);
    const unsigned short* Yb = (const unsigned short*)(wsb + YB_OFF);
    float* fws = (float*)(wsb + FW_OFF);

    int tid = threadIdx.x;
    int lane = tid & 63, wid = tid >> 6;
    int wr = wid >> 2, wc = wid & 3;           // 2 row-groups x 4 col-groups
    int l15 = lane & 15, rgrp = lane >> 4;

    // XCD-bijective swizzle: 512 blocks
    int bid = blockIdx.x;
    int pos = bid >> 3;
    int coltile = pos >> 2;                    // 0..15
    int rowpanel = (bid & 7) * 4 + (pos & 3);  // 0..31
    int rowbase = rowpanel * BM;
    int colbase = coltile * BN;

    // staging: LDS slot t (16B, linear) holds row = t>>2, k-octet = (t&3) ^ ((t>>3)&3)
    int ko_src = ((tid & 3) ^ ((tid >> 3) & 3)) * 8;
    const unsigned short* xk = Xb + (size_t)(rowbase + (tid >> 2)) * DD + ko_src;
    const unsigned short* yk = Yb + (size_t)(colbase + (tid >> 2)) * DD + ko_src;
    unsigned short* adst = Ald + tid * 8;
    unsigned short* bdst = Bld + tid * 8;

    // stage both operands' region (32 KB total) = 4 gll16
#define STG_AB(OFF, RG) do { \
    gll16(xk + (OFF), adst + (RG) * 8192); \
    gll16(xk + (size_t)128 * DD + (OFF), adst + (RG) * 8192 + 4096); \
    gll16(yk + (OFF), bdst + (RG) * 8192); \
    gll16(yk + (size_t)128 * DD + (OFF), bdst + (RG) * 8192 + 4096); } while (0)

    // fragment read bases with read-side XOR folded in
    unsigned a_base = (unsigned)(uintptr_t)(&Ald[0]) + (wr * 128 + l15) * 64
                      + ((rgrp * 16) ^ (((l15 >> 1) & 3) << 4));
    unsigned b_base = (unsigned)(uintptr_t)(&Bld[0]) + (wc * 64 + l15) * 64
                      + ((rgrp * 16) ^ (((l15 >> 1) & 3) << 4));

    f32x4 acc[8][4];
    #pragma unroll
    for (int a = 0; a < 8; ++a)
        #pragma unroll
        for (int b = 0; b < 4; ++b)
            acc[a][b] = (f32x4){0.f, 0.f, 0.f, 0.f};

    // double-buffered fragments: E consumed on even phases, O on odd
    short8 afE[8], afO[8], bfE[4], bfO[4];

#define LD12(AS, BS, RG) do { \
    DSR(BS[0], b_base, (RG) * 16384 + 0); \
    DSR(BS[1], b_base, (RG) * 16384 + 1024); \
    DSR(BS[2], b_base, (RG) * 16384 + 2048); \
    DSR(BS[3], b_base, (RG) * 16384 + 3072); \
    DSR(AS[0], a_base, (RG) * 16384 + 0 * 1024); \
    DSR(AS[1], a_base, (RG) * 16384 + 1 * 1024); \
    DSR(AS[2], a_base, (RG) * 16384 + 2 * 1024); \
    DSR(AS[3], a_base, (RG) * 16384 + 3 * 1024); \
    DSR(AS[4], a_base, (RG) * 16384 + 4 * 1024); \
    DSR(AS[5], a_base, (RG) * 16384 + 5 * 1024); \
    DSR(AS[6], a_base, (RG) * 16384 + 6 * 1024); \
    DSR(AS[7], a_base, (RG) * 16384 + 7 * 1024); } while (0)

#define MF32(AF, BF) do { \
    _Pragma("unroll") \
    for (int mf = 0; mf < 8; ++mf) { \
        acc[mf][0] = MFMA_B(AF[mf], BF[0], acc[mf][0]); \
        acc[mf][1] = MFMA_B(AF[mf], BF[1], acc[mf][1]); \
        acc[mf][2] = MFMA_B(AF[mf], BF[2], acc[mf][2]); \
        acc[mf][3] = MFMA_B(AF[mf], BF[3], acc[mf][3]); \
    } } while (0)

    // phase: STG(p+3) -> counted vmcnt -> BAR1 -> reads(p+1) -> lgkm(12) -> MFMA(32) -> BAR2
#define PH(STG, W, LD, LGN, MF) do { \
    STG; \
    W; \
    BAR(); \
    LD; \
    asm volatile("s_waitcnt lgkmcnt(" #LGN ")" ::: "memory"); \
    __builtin_amdgcn_sched_barrier(0); \
    __builtin_amdgcn_s_setprio(1); \
    MF; \
    __builtin_amdgcn_s_setprio(0); \
    BAR(); \
} while (0)

    // prologue: stage regions 0,1,2 (12 loads); drain rg0; publish; preload phase-0 frags
    STG_AB(0, 0); STG_AB(32, 1); STG_AB(64, 2);
    VM8;
    BAR();
    LD12(afE, bfE, 0);

    // 5 iters x 4 phases (kt = 0,2,4,6,8)
    #pragma unroll 1
    for (int kp = 0; kp < 5; ++kp) {
        PH(STG_AB(96, 3),  VM8, LD12(afO, bfO, 1), 12, MF32(afE, bfE));
        PH(STG_AB(128, 0), VM8, LD12(afE, bfE, 2), 12, MF32(afO, bfO));
        PH(STG_AB(160, 1), VM8, LD12(afO, bfO, 3), 12, MF32(afE, bfE));
        PH(STG_AB(192, 2), VM8, LD12(afE, bfE, 0), 12, MF32(afO, bfO));
        xk += 128; yk += 128;
    }
    // tail: kt = 10,11 (phases 20..23); only (11,h1)->rg3 left to stage
    PH(STG_AB(96, 3), VM8, LD12(afO, bfO, 1), 12, MF32(afE, bfE));
    PH(NOPS,          VM4, LD12(afE, bfE, 2), 12, MF32(afO, bfO));
    PH(NOPS,          VM0, LD12(afO, bfO, 3), 12, MF32(afE, bfE));
    PH(NOPS,          NOPS, NOPS,              0, MF32(afO, bfO));

    // ---- epilogue: per-row top-2 of u = sb*dot - ca*tb (argtop2 == top2 of inner; sa>0) ----
    int colb = colbase + wc * 64 + l15;
    float sbv[4], tbv[4];
    #pragma unroll
    for (int nf = 0; nf < 4; ++nf) { sbv[nf] = fws[S_L + colb + nf * 16]; tbv[nf] = fws[T_L + colb + nf * 16]; }

    float m1[32], m2[32];
    #pragma unroll
    for (int mf = 0; mf < 8; ++mf) {
        int rw = rowbase + wr * 128 + mf * 16 + rgrp * 4;
        #pragma unroll
        for (int j = 0; j < 4; ++j) {
            float ca = fws[CA_T + rw + j];
            int tgj = tgt[rw + j];
            float a = -3.4e38f, b = -3.4e38f;
            #pragma unroll
            for (int nf = 0; nf < 4; ++nf) {
                float u = sbv[nf] * acc[mf][nf][j] - ca * tbv[nf];
                if (colb + nf * 16 == tgj) u = -3.4e38f;
                float n1 = fmaxf(a, u);
                b = fmaxf(b, fminf(a, u));
                a = n1;
            }
            m1[mf * 4 + j] = a; m2[mf * 4 + j] = b;
        }
    }
    #pragma unroll
    for (int mask = 1; mask <= 8; mask <<= 1)
        #pragma unroll
        for (int i = 0; i < 32; ++i) {
            float o1 = __shfl_xor(m1[i], mask);
            float o2 = __shfl_xor(m2[i], mask);
            float n1 = fmaxf(m1[i], o1);
            m2[i] = fmaxf(fminf(m1[i], o1), fmaxf(m2[i], o2));
            m1[i] = n1;
        }
    if (l15 == 0) {
        #pragma unroll
        for (int mf = 0; mf < 8; ++mf)
            #pragma unroll
            for (int j = 0; j < 4; ++j) {
                int rl = wr * 128 + mf * 16 + rgrp * 4 + j;
                red[rl][wc][0] = m1[mf * 4 + j];
                red[rl][wc][1] = m2[mf * 4 + j];
            }
    }
    __syncthreads();
    if (tid < 256) {
        float p1 = -3.4e38f, p2 = -3.4e38f;
        #pragma unroll
        for (int g = 0; g < 4; ++g) {
            float a1 = red[tid][g][0], a2 = red[tid][g][1];
            float n1 = fmaxf(p1, a1);
            p2 = fmaxf(fminf(p1, a1), fmaxf(p2, a2));
            p1 = n1;
        }
        int row = rowbase + tid;
        fws[PART + ((size_t)row * NCOLT + coltile) * 2 + 0] = p1;
        fws[PART + ((size_t)row * NCOLT + coltile) * 2 + 1] = p2;
    }
}

// ---------------- final: merge partials, arccosh on winners, loss ----------------
__global__ void final_kernel(const char* __restrict__ wsb, const float* __restrict__ curv_log,
                             float* __restrict__ out) {
    const float* fws = (const float*)(wsb + FW_OFF);
    int row = blockIdx.x * 256 + threadIdx.x;
    if (row >= MM) return;
    float curv = __expf(curv_log[0]);
    float rsc = rsqrtf(curv);
    const float* p = fws + PART + (size_t)row * (NCOLT * 2);
    float p1 = -3.4e38f, p2 = -3.4e38f;
    #pragma unroll
    for (int s = 0; s < NCOLT; ++s) {
        float a1 = p[s * 2], a2 = p[s * 2 + 1];
        float n1 = fmaxf(p1, a1);
        p2 = fmaxf(fminf(p1, a1), fmaxf(p2, a2));
        p1 = n1;
    }
    float sa = fws[S_T + row];
    float i1 = sa * p1, i2 = sa * p2;          // back to Lorentz inner
    float cd1 = fmaxf(-curv * i1, 1.0f + EPSF);
    float d1 = __logf(cd1 + sqrtf(cd1 * cd1 - 1.0f)) * rsc;
    float cd2 = fmaxf(-curv * i2, 1.0f + EPSF);
    float d2 = __logf(cd2 + sqrtf(cd2 * cd2 - 1.0f)) * rsc;
    float dp = fws[POS + row];
    float denom = __expf(-dp) + __expf(-d1) + __expf(-d2);
    out[row] = __logf(denom) + dp;
}

extern "C" void kernel_launch(void* const* d_in, const int* in_sizes, int n_in,
                              void* d_out, int out_size, void* d_ws, size_t ws_size,
                              hipStream_t stream) {
    const float* X = (const float*)d_in[0];
    const float* Y = (const float*)d_in[1];
    const int* tgt = (const int*)d_in[2];
    const float* curv_log = (const float*)d_in[3];
    const float* ta_log = (const float*)d_in[4];
    const float* la_log = (const float*)d_in[5];
    char* wsb = (char*)d_ws;
    float* out = (float*)d_out;

    prep_conv_kernel<<<(MM + CC) / 4, 256, 0, stream>>>(X, Y, curv_log, ta_log, la_log, wsb);
    pos_kernel<<<MM / 4, 256, 0, stream>>>(X, Y, tgt, curv_log, wsb);
    main_kernel<<<NROWT * NCOLT, TPB, 0, stream>>>(tgt, wsb);
    final_kernel<<<MM / 256, 256, 0, stream>>>(wsb, curv_log, out);
}